// Round 7
// baseline (319.591 us; speedup 1.0000x reference)
//
#include <hip/hip_runtime.h>
#include <math.h>

typedef short short8 __attribute__((ext_vector_type(8)));
typedef float f32x4 __attribute__((ext_vector_type(4)));

#define WP 132   // wtile pitch (f32)
#define OP 136   // otile pitch (bf16)

__device__ __forceinline__ short f2bf(float x) {
    unsigned u = __float_as_uint(x);
    u += 0x7fffu + ((u >> 16) & 1u);
    return (short)(u >> 16);
}

// ---------------------------------------------------------------------------
// K1: in-degree histogram. dst is streamed non-temporally (protect degi in L2).
__global__ void k_deg(const int* __restrict__ dst, int* __restrict__ degi, int E) {
    int i = blockIdx.x * 256 + threadIdx.x;
    if (i < E) atomicAdd(&degi[__builtin_nontemporal_load(&dst[i])], 1);
}

// ---------------------------------------------------------------------------
// CSR build. scan_a also emits dis = rsqrt(deg+1).
__global__ void k_scan_a(const int* __restrict__ degi, int* __restrict__ rowptr,
                         int* __restrict__ csums, float* __restrict__ dis, int n) {
    __shared__ int sdata[256];
    int tid = threadIdx.x;
    int idx = blockIdx.x * 1024 + tid * 4;
    int v[4];
#pragma unroll
    for (int j = 0; j < 4; ++j) {
        v[j] = (idx + j < n) ? degi[idx + j] : 0;
        if (idx + j < n) dis[idx + j] = rsqrtf((float)(v[j] + 1));
    }
    int tsum = v[0] + v[1] + v[2] + v[3];
    sdata[tid] = tsum;
    __syncthreads();
    for (int off = 1; off < 256; off <<= 1) {
        int add = (tid >= off) ? sdata[tid - off] : 0;
        __syncthreads();
        sdata[tid] += add;
        __syncthreads();
    }
    int excl = sdata[tid] - tsum;
    int run = 0;
#pragma unroll
    for (int j = 0; j < 4; ++j) {
        if (idx + j < n) rowptr[idx + j] = excl + run;
        run += v[j];
    }
    if (tid == 255) csums[blockIdx.x] = sdata[255];
}

__global__ void k_scan_b(int* __restrict__ csums, int nch) {
    __shared__ int sdata[256];
    int tid = threadIdx.x;
    int v[4];
#pragma unroll
    for (int j = 0; j < 4; ++j) {
        int i = tid * 4 + j;
        v[j] = (i < nch) ? csums[i] : 0;
    }
    int tsum = v[0] + v[1] + v[2] + v[3];
    sdata[tid] = tsum;
    __syncthreads();
    for (int off = 1; off < 256; off <<= 1) {
        int add = (tid >= off) ? sdata[tid - off] : 0;
        __syncthreads();
        sdata[tid] += add;
        __syncthreads();
    }
    int excl = sdata[tid] - tsum;
    int run = 0;
#pragma unroll
    for (int j = 0; j < 4; ++j) {
        int i = tid * 4 + j;
        if (i < nch) csums[i] = excl + run;
        run += v[j];
    }
}

__global__ void k_scan_c(int* __restrict__ rowptr, int* __restrict__ cur,
                         const int* __restrict__ csums, int n, int E) {
    int idx = blockIdx.x * 1024 + threadIdx.x * 4;
    int add = csums[blockIdx.x];
#pragma unroll
    for (int j = 0; j < 4; ++j) {
        if (idx + j < n) {
            int r = rowptr[idx + j] + add;
            rowptr[idx + j] = r;
            cur[idx + j] = r;
        }
    }
    if (blockIdx.x == 0 && threadIdx.x == 0) rowptr[n] = E;
}

// fill, XCD-partitioned by dst range (locality heuristic; correctness holds
// under any blockIdx->XCD mapping). src/dst read unconditionally (coalesced,
// L3-served for 7 of 8 passes) and non-temporally (keep esrc lines in L2).
__global__ void k_fill_xcd(const int* __restrict__ src, const int* __restrict__ dst,
                           int* __restrict__ cur, int* __restrict__ esrc,
                           int E, int N) {
    int xcd = blockIdx.x & 7;
    int lo = (int)((long long)N * xcd / 8);
    int hi = (int)((long long)N * (xcd + 1) / 8);
    int nb = gridDim.x >> 3;
    int bi = blockIdx.x >> 3;
    for (int i = bi * 256 + threadIdx.x; i < E; i += nb * 256) {
        int d = __builtin_nontemporal_load(&dst[i]);
        int s = __builtin_nontemporal_load(&src[i]);
        if (d >= lo && d < hi) {
            int pos = atomicAdd(&cur[d], 1);
            esrc[pos] = s;
        }
    }
}

// ---------------------------------------------------------------------------
// Weight tables: T1T[f][c] = bf16((emb@W1)^T), W2T[f][k] = bf16(W2^T)
__global__ void k_tabs(const float* __restrict__ emb, const float* __restrict__ W1,
                       const float* __restrict__ W2,
                       short* __restrict__ T1T, short* __restrict__ W2T) {
    int id = blockIdx.x * 256 + threadIdx.x;
    if (id < 128 * 128) {
        int f = id >> 7, c = id & 127;
        float acc = 0.f;
#pragma unroll
        for (int k = 0; k < 64; ++k) acc += emb[c * 64 + k] * W1[k * 128 + f];
        T1T[id] = f2bf(acc);
    } else {
        int id2 = id - 128 * 128;
        if (id2 < 64 * 128) {
            int f = id2 >> 7, k = id2 & 127;
            W2T[id2] = f2bf(W2[k * 64 + f]);
        }
    }
}

// ---------------------------------------------------------------------------
// Fused layer1+layer2 per 16-node tile (LDS vocab histogram -> MFMA -> MFMA)
__global__ __launch_bounds__(256) void k_fused(
        const int* __restrict__ rowptr, const int* __restrict__ esrc,
        const int* __restrict__ nid, const float* __restrict__ dis,
        const short* __restrict__ T1T, const short* __restrict__ W2T,
        const float* __restrict__ b1, unsigned short* __restrict__ g, int N) {
    __shared__ float wtile[16 * WP];
    __shared__ unsigned short otile[16 * OP];
    __shared__ int srp[17];
    int tid = threadIdx.x;
    int v0 = blockIdx.x * 16;
    int nloc = min(16, N - v0);

    if (tid <= nloc) srp[tid] = rowptr[v0 + tid];
    for (int i = tid; i < 16 * WP; i += 256) wtile[i] = 0.f;
    __syncthreads();

    if (tid < nloc) {                       // self loops
        int v = v0 + tid;
        atomicAdd(&wtile[tid * WP + nid[v]], dis[v]);
    }
    int e0 = srp[0], e1 = srp[nloc];
    for (int i = e0 + tid; i < e1; i += 256) {
        int s = esrc[i];
        int lo = 0, hi = nloc;
        while (hi - lo > 1) {
            int mid = (lo + hi) >> 1;
            if (i >= srp[mid]) lo = mid; else hi = mid;
        }
        atomicAdd(&wtile[lo * WP + nid[s]], dis[s]);
    }
    __syncthreads();

    int wid = tid >> 6, lane = tid & 63;
    int m = lane & 15, g4 = lane >> 4;

    short8 a[4];
#pragma unroll
    for (int s = 0; s < 4; ++s) {
        float av[8];
        *(f32x4*)(av)     = *(const f32x4*)&wtile[m * WP + g4 * 8 + s * 32];
        *(f32x4*)(av + 4) = *(const f32x4*)&wtile[m * WP + g4 * 8 + s * 32 + 4];
        short8 f;
#pragma unroll
        for (int i = 0; i < 8; ++i) f[i] = f2bf(av[i]);
        a[s] = f;
    }
    float dvals[4];
#pragma unroll
    for (int r = 0; r < 4; ++r) {
        int v = v0 + g4 * 4 + r;
        dvals[r] = (v < N) ? dis[v] : 0.f;
    }

#pragma unroll
    for (int t = 0; t < 2; ++t) {
        int nt = wid * 2 + t;
        f32x4 acc = {0.f, 0.f, 0.f, 0.f};
        const short8* bp = (const short8*)(T1T + (size_t)(nt * 16 + m) * 128 + g4 * 8);
#pragma unroll
        for (int s = 0; s < 4; ++s)
            acc = __builtin_amdgcn_mfma_f32_16x16x32_bf16(a[s], bp[s * 4], acc, 0, 0, 0);
        int col = nt * 16 + m;
        float bb = b1[col];
#pragma unroll
        for (int r = 0; r < 4; ++r) {
            int row = g4 * 4 + r;
            otile[row * OP + col] =
                (unsigned short)f2bf(fmaxf(dvals[r] * acc[r] + bb, 0.f));
        }
    }
    __syncthreads();

    short8 a2[4];
#pragma unroll
    for (int s = 0; s < 4; ++s)
        a2[s] = *(const short8*)&otile[m * OP + g4 * 8 + s * 32];
    {
        int nt2 = wid;
        f32x4 acc = {0.f, 0.f, 0.f, 0.f};
        const short8* bp = (const short8*)(W2T + (size_t)(nt2 * 16 + m) * 128 + g4 * 8);
#pragma unroll
        for (int s = 0; s < 4; ++s)
            acc = __builtin_amdgcn_mfma_f32_16x16x32_bf16(a2[s], bp[s * 4], acc, 0, 0, 0);
#pragma unroll
        for (int r = 0; r < 4; ++r) {
            int row = g4 * 4 + r;
            if (row < nloc)
                g[(size_t)(v0 + row) * 64 + nt2 * 16 + m] =
                    (unsigned short)f2bf(dvals[r] * acc[r]);
        }
    }
}

// ---------------------------------------------------------------------------
// Fused gather + mean-pool + fc + sigmoid. One block per graph (batch sorted ->
// contiguous node range, found by binary search). No x buffer, no atomics.
__device__ __forceinline__ int lower_bound(const int* __restrict__ a, int n, int key) {
    int lo = 0, hi = n;
    while (lo < hi) {
        int mid = (lo + hi) >> 1;
        if (a[mid] < key) lo = mid + 1; else hi = mid;
    }
    return lo;
}

__global__ __launch_bounds__(256) void k_gpool(
        const int* __restrict__ batch, const int* __restrict__ rowptr,
        const int* __restrict__ esrc, const unsigned short* __restrict__ g,
        const float* __restrict__ dis, const float* __restrict__ b2,
        const float* __restrict__ fc_w, const float* __restrict__ fc_b,
        float* __restrict__ out, int n) {
    __shared__ float red[4][64];
    int gi = blockIdx.x;
    int tid = threadIdx.x, wid = tid >> 6, lane = tid & 63;
    int half = lane >> 5, l32 = lane & 31;
    int s0n = lower_bound(batch, n, gi);
    int e0n = lower_bound(batch, n, gi + 1);

    const unsigned* g32 = (const unsigned*)g;
    float2 accp = {0.f, 0.f};                 // pooled sum (half0 lanes)
    float2 bb = ((const float2*)b2)[l32];

    for (int v = s0n + wid; v < e0n; v += 4) {
        float2 a0 = {0.f, 0.f}, a1 = {0.f, 0.f}, a2 = {0.f, 0.f}, a3 = {0.f, 0.f};
        float2 a4 = {0.f, 0.f}, a5 = {0.f, 0.f}, a6 = {0.f, 0.f}, a7 = {0.f, 0.f};
        if (half == 0) {                       // self loop
            unsigned u = g32[(size_t)v * 32 + l32];
            a7.x += __uint_as_float(u << 16);
            a7.y += __uint_as_float(u & 0xffff0000u);
        }
        int e = rowptr[v], re = rowptr[v + 1];
        for (; e + 16 <= re; e += 16) {
            int sl = esrc[e + (lane & 15)];
            int s0 = __shfl(sl, 0 + half, 16), s1 = __shfl(sl, 2 + half, 16);
            int s2 = __shfl(sl, 4 + half, 16), s3 = __shfl(sl, 6 + half, 16);
            int s4 = __shfl(sl, 8 + half, 16), s5 = __shfl(sl, 10 + half, 16);
            int s6 = __shfl(sl, 12 + half, 16), s7 = __shfl(sl, 14 + half, 16);
            unsigned u0 = g32[(size_t)s0 * 32 + l32];
            unsigned u1 = g32[(size_t)s1 * 32 + l32];
            unsigned u2 = g32[(size_t)s2 * 32 + l32];
            unsigned u3 = g32[(size_t)s3 * 32 + l32];
            unsigned u4 = g32[(size_t)s4 * 32 + l32];
            unsigned u5 = g32[(size_t)s5 * 32 + l32];
            unsigned u6 = g32[(size_t)s6 * 32 + l32];
            unsigned u7 = g32[(size_t)s7 * 32 + l32];
            a0.x += __uint_as_float(u0 << 16); a0.y += __uint_as_float(u0 & 0xffff0000u);
            a1.x += __uint_as_float(u1 << 16); a1.y += __uint_as_float(u1 & 0xffff0000u);
            a2.x += __uint_as_float(u2 << 16); a2.y += __uint_as_float(u2 & 0xffff0000u);
            a3.x += __uint_as_float(u3 << 16); a3.y += __uint_as_float(u3 & 0xffff0000u);
            a4.x += __uint_as_float(u4 << 16); a4.y += __uint_as_float(u4 & 0xffff0000u);
            a5.x += __uint_as_float(u5 << 16); a5.y += __uint_as_float(u5 & 0xffff0000u);
            a6.x += __uint_as_float(u6 << 16); a6.y += __uint_as_float(u6 & 0xffff0000u);
            a7.x += __uint_as_float(u7 << 16); a7.y += __uint_as_float(u7 & 0xffff0000u);
        }
        for (; e + 2 <= re; e += 2) {
            int s = esrc[e + half];
            unsigned u = g32[(size_t)s * 32 + l32];
            a0.x += __uint_as_float(u << 16);
            a0.y += __uint_as_float(u & 0xffff0000u);
        }
        if (e < re && half == 0) {
            int s = esrc[e];
            unsigned u = g32[(size_t)s * 32 + l32];
            a1.x += __uint_as_float(u << 16);
            a1.y += __uint_as_float(u & 0xffff0000u);
        }
        float2 tot;
        tot.x = ((a0.x + a1.x) + (a2.x + a3.x)) + ((a4.x + a5.x) + (a6.x + a7.x));
        tot.y = ((a0.y + a1.y) + (a2.y + a3.y)) + ((a4.y + a5.y) + (a6.y + a7.y));
        tot.x += __shfl_xor(tot.x, 32);
        tot.y += __shfl_xor(tot.y, 32);
        if (half == 0) {
            float dv = dis[v];
            accp.x += fmaxf(dv * tot.x + bb.x, 0.f);
            accp.y += fmaxf(dv * tot.y + bb.y, 0.f);
        }
    }
    if (half == 0) {
        red[wid][l32] = accp.x;
        red[wid][32 + l32] = accp.y;
    }
    __syncthreads();
    if (wid == 0) {
        float a = red[0][lane] + red[1][lane] + red[2][lane] + red[3][lane];
        int f = (lane < 32) ? (2 * lane) : (2 * (lane - 32) + 1);
        float cnt = fmaxf((float)(e0n - s0n), 1.0f);
        a = (a / cnt) * fc_w[f];
#pragma unroll
        for (int off = 32; off >= 1; off >>= 1) a += __shfl_down(a, off);
        if (lane == 0) out[gi] = 1.0f / (1.0f + expf(-(a + fc_b[0])));
    }
}

extern "C" void kernel_launch(void* const* d_in, const int* in_sizes, int n_in,
                              void* d_out, int out_size, void* d_ws, size_t ws_size,
                              hipStream_t stream) {
    const int*   nid   = (const int*)d_in[0];
    const int*   eidx  = (const int*)d_in[1];
    const int*   batch = (const int*)d_in[2];
    const float* emb   = (const float*)d_in[3];
    const float* W1    = (const float*)d_in[4];
    const float* b1    = (const float*)d_in[5];
    const float* W2    = (const float*)d_in[6];
    const float* b2    = (const float*)d_in[7];
    const float* fcw   = (const float*)d_in[8];
    const float* fcb   = (const float*)d_in[9];

    const int N = in_sizes[0];
    const int E = in_sizes[1] / 2;
    const int G = out_size;
    const int* src = eidx;
    const int* dst = eidx + E;

    char* p = (char*)d_ws;
    auto alloc = [&](size_t bytes) {
        char* r = p;
        p += (bytes + 255) & ~(size_t)255;
        return r;
    };
    int*   degi   = (int*)  alloc((size_t)N * 4);
    float* dis    = (float*)alloc((size_t)N * 4);
    short* T1T    = (short*)alloc(128 * 128 * 2);
    short* W2T    = (short*)alloc(64 * 128 * 2);
    int*   rowptr = (int*)  alloc((size_t)(N + 1) * 4);
    int*   cur    = (int*)  alloc((size_t)N * 4);
    int*   csums  = (int*)  alloc(4096 * 4);
    int*   esrc   = (int*)  alloc((size_t)E * 4);
    unsigned short* g = (unsigned short*)alloc((size_t)N * 64 * 2);

    hipMemsetAsync(degi, 0, (size_t)N * 4, stream);

    k_deg<<<(E + 255) / 256, 256, 0, stream>>>(dst, degi, E);

    int nch = (N + 1023) / 1024;
    k_scan_a<<<nch, 256, 0, stream>>>(degi, rowptr, csums, dis, N);
    k_scan_b<<<1, 256, 0, stream>>>(csums, nch);
    k_scan_c<<<nch, 256, 0, stream>>>(rowptr, cur, csums, N, E);
    k_fill_xcd<<<2048, 256, 0, stream>>>(src, dst, cur, esrc, E, N);

    k_tabs<<<96, 256, 0, stream>>>(emb, W1, W2, T1T, W2T);

    k_fused<<<(N + 15) / 16, 256, 0, stream>>>(rowptr, esrc, nid, dis, T1T, W2T,
                                               b1, g, N);

    k_gpool<<<G, 256, 0, stream>>>(batch, rowptr, esrc, g, dis, b2, fcw, fcb,
                                   (float*)d_out, N);
}

// Round 8
// 251.266 us; speedup vs baseline: 1.2719x; 1.2719x over previous
//
#include <hip/hip_runtime.h>
#include <math.h>

typedef short short8 __attribute__((ext_vector_type(8)));
typedef float f32x4 __attribute__((ext_vector_type(4)));

#define WP 132   // wtile pitch (f32)
#define OP 136   // otile pitch (bf16)

__device__ __forceinline__ short f2bf(float x) {
    unsigned u = __float_as_uint(x);
    u += 0x7fffu + ((u >> 16) & 1u);
    return (short)(u >> 16);
}

// ---------------------------------------------------------------------------
// K1: in-degree histogram. dst is a read-once stream -> non-temporal.
__global__ void k_deg(const int* __restrict__ dst, int* __restrict__ degi, int E) {
    int i = blockIdx.x * 256 + threadIdx.x;
    if (i < E) atomicAdd(&degi[__builtin_nontemporal_load(&dst[i])], 1);
}

// ---------------------------------------------------------------------------
// CSR build. scan_a also emits dis = rsqrt(deg+1).
__global__ void k_scan_a(const int* __restrict__ degi, int* __restrict__ rowptr,
                         int* __restrict__ csums, float* __restrict__ dis, int n) {
    __shared__ int sdata[256];
    int tid = threadIdx.x;
    int idx = blockIdx.x * 1024 + tid * 4;
    int v[4];
#pragma unroll
    for (int j = 0; j < 4; ++j) {
        v[j] = (idx + j < n) ? degi[idx + j] : 0;
        if (idx + j < n) dis[idx + j] = rsqrtf((float)(v[j] + 1));
    }
    int tsum = v[0] + v[1] + v[2] + v[3];
    sdata[tid] = tsum;
    __syncthreads();
    for (int off = 1; off < 256; off <<= 1) {
        int add = (tid >= off) ? sdata[tid - off] : 0;
        __syncthreads();
        sdata[tid] += add;
        __syncthreads();
    }
    int excl = sdata[tid] - tsum;
    int run = 0;
#pragma unroll
    for (int j = 0; j < 4; ++j) {
        if (idx + j < n) rowptr[idx + j] = excl + run;
        run += v[j];
    }
    if (tid == 255) csums[blockIdx.x] = sdata[255];
}

__global__ void k_scan_b(int* __restrict__ csums, int nch) {
    __shared__ int sdata[256];
    int tid = threadIdx.x;
    int v[4];
#pragma unroll
    for (int j = 0; j < 4; ++j) {
        int i = tid * 4 + j;
        v[j] = (i < nch) ? csums[i] : 0;
    }
    int tsum = v[0] + v[1] + v[2] + v[3];
    sdata[tid] = tsum;
    __syncthreads();
    for (int off = 1; off < 256; off <<= 1) {
        int add = (tid >= off) ? sdata[tid - off] : 0;
        __syncthreads();
        sdata[tid] += add;
        __syncthreads();
    }
    int excl = sdata[tid] - tsum;
    int run = 0;
#pragma unroll
    for (int j = 0; j < 4; ++j) {
        int i = tid * 4 + j;
        if (i < nch) csums[i] = excl + run;
        run += v[j];
    }
}

__global__ void k_scan_c(int* __restrict__ rowptr, int* __restrict__ cur,
                         const int* __restrict__ csums, int n, int E) {
    int idx = blockIdx.x * 1024 + threadIdx.x * 4;
    int add = csums[blockIdx.x];
#pragma unroll
    for (int j = 0; j < 4; ++j) {
        if (idx + j < n) {
            int r = rowptr[idx + j] + add;
            rowptr[idx + j] = r;
            cur[idx + j] = r;
        }
    }
    if (blockIdx.x == 0 && threadIdx.x == 0) rowptr[n] = E;
}

// fill, XCD-partitioned by dst range (locality heuristic; correctness holds
// under any blockIdx->XCD mapping). src/dst read unconditionally (coalesced,
// lines L3-served across the 8 passes).
__global__ void k_fill_xcd(const int* __restrict__ src, const int* __restrict__ dst,
                           int* __restrict__ cur, int* __restrict__ esrc,
                           int E, int N) {
    int xcd = blockIdx.x & 7;
    int lo = (int)((long long)N * xcd / 8);
    int hi = (int)((long long)N * (xcd + 1) / 8);
    int nb = gridDim.x >> 3;
    int bi = blockIdx.x >> 3;
    for (int i = bi * 256 + threadIdx.x; i < E; i += nb * 256) {
        int d = dst[i];
        int s = src[i];
        if (d >= lo && d < hi) {
            int pos = atomicAdd(&cur[d], 1);
            esrc[pos] = s;
        }
    }
}

// ---------------------------------------------------------------------------
// Weight tables: T1T[f][c] = bf16((emb@W1)^T), W2T[f][k] = bf16(W2^T)
__global__ void k_tabs(const float* __restrict__ emb, const float* __restrict__ W1,
                       const float* __restrict__ W2,
                       short* __restrict__ T1T, short* __restrict__ W2T) {
    int id = blockIdx.x * 256 + threadIdx.x;
    if (id < 128 * 128) {
        int f = id >> 7, c = id & 127;
        float acc = 0.f;
#pragma unroll
        for (int k = 0; k < 64; ++k) acc += emb[c * 64 + k] * W1[k * 128 + f];
        T1T[id] = f2bf(acc);
    } else {
        int id2 = id - 128 * 128;
        if (id2 < 64 * 128) {
            int f = id2 >> 7, k = id2 & 127;
            W2T[id2] = f2bf(W2[k * 64 + f]);
        }
    }
}

// ---------------------------------------------------------------------------
// Fused layer1+layer2 per 16-node tile (LDS vocab histogram -> MFMA -> MFMA)
__global__ __launch_bounds__(256) void k_fused(
        const int* __restrict__ rowptr, const int* __restrict__ esrc,
        const int* __restrict__ nid, const float* __restrict__ dis,
        const short* __restrict__ T1T, const short* __restrict__ W2T,
        const float* __restrict__ b1, unsigned short* __restrict__ g, int N) {
    __shared__ float wtile[16 * WP];
    __shared__ unsigned short otile[16 * OP];
    __shared__ int srp[17];
    int tid = threadIdx.x;
    int v0 = blockIdx.x * 16;
    int nloc = min(16, N - v0);

    if (tid <= nloc) srp[tid] = rowptr[v0 + tid];
    for (int i = tid; i < 16 * WP; i += 256) wtile[i] = 0.f;
    __syncthreads();

    if (tid < nloc) {                       // self loops
        int v = v0 + tid;
        atomicAdd(&wtile[tid * WP + nid[v]], dis[v]);
    }
    int e0 = srp[0], e1 = srp[nloc];
    for (int i = e0 + tid; i < e1; i += 256) {
        int s = esrc[i];
        int lo = 0, hi = nloc;
        while (hi - lo > 1) {
            int mid = (lo + hi) >> 1;
            if (i >= srp[mid]) lo = mid; else hi = mid;
        }
        atomicAdd(&wtile[lo * WP + nid[s]], dis[s]);
    }
    __syncthreads();

    int wid = tid >> 6, lane = tid & 63;
    int m = lane & 15, g4 = lane >> 4;

    short8 a[4];
#pragma unroll
    for (int s = 0; s < 4; ++s) {
        float av[8];
        *(f32x4*)(av)     = *(const f32x4*)&wtile[m * WP + g4 * 8 + s * 32];
        *(f32x4*)(av + 4) = *(const f32x4*)&wtile[m * WP + g4 * 8 + s * 32 + 4];
        short8 f;
#pragma unroll
        for (int i = 0; i < 8; ++i) f[i] = f2bf(av[i]);
        a[s] = f;
    }
    float dvals[4];
#pragma unroll
    for (int r = 0; r < 4; ++r) {
        int v = v0 + g4 * 4 + r;
        dvals[r] = (v < N) ? dis[v] : 0.f;
    }

#pragma unroll
    for (int t = 0; t < 2; ++t) {
        int nt = wid * 2 + t;
        f32x4 acc = {0.f, 0.f, 0.f, 0.f};
        const short8* bp = (const short8*)(T1T + (size_t)(nt * 16 + m) * 128 + g4 * 8);
#pragma unroll
        for (int s = 0; s < 4; ++s)
            acc = __builtin_amdgcn_mfma_f32_16x16x32_bf16(a[s], bp[s * 4], acc, 0, 0, 0);
        int col = nt * 16 + m;
        float bb = b1[col];
#pragma unroll
        for (int r = 0; r < 4; ++r) {
            int row = g4 * 4 + r;
            otile[row * OP + col] =
                (unsigned short)f2bf(fmaxf(dvals[r] * acc[r] + bb, 0.f));
        }
    }
    __syncthreads();

    short8 a2[4];
#pragma unroll
    for (int s = 0; s < 4; ++s)
        a2[s] = *(const short8*)&otile[m * OP + g4 * 8 + s * 32];
    {
        int nt2 = wid;
        f32x4 acc = {0.f, 0.f, 0.f, 0.f};
        const short8* bp = (const short8*)(W2T + (size_t)(nt2 * 16 + m) * 128 + g4 * 8);
#pragma unroll
        for (int s = 0; s < 4; ++s)
            acc = __builtin_amdgcn_mfma_f32_16x16x32_bf16(a2[s], bp[s * 4], acc, 0, 0, 0);
#pragma unroll
        for (int r = 0; r < 4; ++r) {
            int row = g4 * 4 + r;
            if (row < nloc)
                g[(size_t)(v0 + row) * 64 + nt2 * 16 + m] =
                    (unsigned short)f2bf(dvals[r] * acc[r]);
        }
    }
}

// ---------------------------------------------------------------------------
// K7: gather(bf16) + relu -> x. ONE 16-LANE QUARTER-WAVE PER NODE; lane owns
// 4 features (uint2 = 8B of the 128B row). Chunks of 8 edges with clamped
// indices: all 8 row-loads always issue (32 rows in flight per wave), adds
// masked by validity. No cross-lane reduction; coalesced float4 store.
__global__ void k_gather2(const int* __restrict__ rowptr, const int* __restrict__ esrc,
                          const unsigned short* __restrict__ g,
                          const float* __restrict__ dis, const float* __restrict__ b2,
                          float* __restrict__ x, int n) {
    int v = (blockIdx.x * 256 + threadIdx.x) >> 4;
    int l = threadIdx.x & 15;
    if (v >= n) return;
    const uint2* g64 = (const uint2*)g;

    // self loop
    uint2 su = g64[(size_t)v * 16 + l];
    f32x4 acc;
    acc[0] = __uint_as_float(su.x << 16);
    acc[1] = __uint_as_float(su.x & 0xffff0000u);
    acc[2] = __uint_as_float(su.y << 16);
    acc[3] = __uint_as_float(su.y & 0xffff0000u);

    int e = rowptr[v], re = rowptr[v + 1];
    while (e < re) {
        int idx = e + (l & 7);
        int sl = esrc[min(idx, re - 1)];
        int cnt = re - e;                      // valid edges this chunk (>=1)
        uint2 u[8];
#pragma unroll
        for (int j = 0; j < 8; ++j) {
            int s = __shfl(sl, j, 8);
            u[j] = g64[(size_t)s * 16 + l];
        }
#pragma unroll
        for (int j = 0; j < 8; ++j) {
            float mask = (j < cnt) ? 1.f : 0.f;
            acc[0] += mask * __uint_as_float(u[j].x << 16);
            acc[1] += mask * __uint_as_float(u[j].x & 0xffff0000u);
            acc[2] += mask * __uint_as_float(u[j].y << 16);
            acc[3] += mask * __uint_as_float(u[j].y & 0xffff0000u);
        }
        e += 8;
    }
    float dv = dis[v];
    f32x4 bb = *(const f32x4*)(b2 + l * 4);
    f32x4 r;
#pragma unroll
    for (int j = 0; j < 4; ++j) r[j] = fmaxf(dv * acc[j] + bb[j], 0.f);
    *(f32x4*)(x + (size_t)v * 64 + l * 4) = r;
}

// ---------------------------------------------------------------------------
// Graph boundaries from sorted batch (gstart/gend pre-zeroed for empty graphs)
__global__ void k_bounds(const int* __restrict__ batch, int* __restrict__ gstart,
                         int* __restrict__ gend, int n) {
    int i = blockIdx.x * 256 + threadIdx.x;
    if (i >= n) return;
    int b = batch[i];
    if (i == 0 || batch[i - 1] != b) gstart[b] = i;
    if (i == n - 1 || batch[i + 1] != b) gend[b] = i + 1;
}

// Pool + fc + sigmoid: one block per graph, coalesced segment mean, no atomics
__global__ __launch_bounds__(256) void k_pool2(
        const float* __restrict__ x, const int* __restrict__ gstart,
        const int* __restrict__ gend, const float* __restrict__ fc_w,
        const float* __restrict__ fc_b, float* __restrict__ out) {
    __shared__ float red[4][64];
    int gi = blockIdx.x;
    int tid = threadIdx.x, wid = tid >> 6, lane = tid & 63;
    int s = gstart[gi], epos = gend[gi];
    float acc = 0.f;
    for (int r = s + wid; r < epos; r += 4) acc += x[(size_t)r * 64 + lane];
    red[wid][lane] = acc;
    __syncthreads();
    if (wid == 0) {
        float a = red[0][lane] + red[1][lane] + red[2][lane] + red[3][lane];
        float cnt = fmaxf((float)(epos - s), 1.0f);
        a = (a / cnt) * fc_w[lane];
#pragma unroll
        for (int off = 32; off >= 1; off >>= 1) a += __shfl_down(a, off);
        if (lane == 0) out[gi] = 1.0f / (1.0f + expf(-(a + fc_b[0])));
    }
}

extern "C" void kernel_launch(void* const* d_in, const int* in_sizes, int n_in,
                              void* d_out, int out_size, void* d_ws, size_t ws_size,
                              hipStream_t stream) {
    const int*   nid   = (const int*)d_in[0];
    const int*   eidx  = (const int*)d_in[1];
    const int*   batch = (const int*)d_in[2];
    const float* emb   = (const float*)d_in[3];
    const float* W1    = (const float*)d_in[4];
    const float* b1    = (const float*)d_in[5];
    const float* W2    = (const float*)d_in[6];
    const float* b2    = (const float*)d_in[7];
    const float* fcw   = (const float*)d_in[8];
    const float* fcb   = (const float*)d_in[9];

    const int N = in_sizes[0];
    const int E = in_sizes[1] / 2;
    const int G = out_size;
    const int* src = eidx;
    const int* dst = eidx + E;

    char* p = (char*)d_ws;
    auto alloc = [&](size_t bytes) {
        char* r = p;
        p += (bytes + 255) & ~(size_t)255;
        return r;
    };
    int*   degi   = (int*)  alloc((size_t)N * 4);
    float* dis    = (float*)alloc((size_t)N * 4);
    short* T1T    = (short*)alloc(128 * 128 * 2);
    short* W2T    = (short*)alloc(64 * 128 * 2);
    int*   rowptr = (int*)  alloc((size_t)(N + 1) * 4);
    int*   cur    = (int*)  alloc((size_t)N * 4);
    int*   csums  = (int*)  alloc(4096 * 4);
    int*   esrc   = (int*)  alloc((size_t)E * 4);
    unsigned short* g = (unsigned short*)alloc((size_t)N * 64 * 2);
    float* x      = (float*)alloc((size_t)N * 64 * 4);
    int*   gstart = (int*)  alloc((size_t)G * 4);
    int*   gend   = (int*)  alloc((size_t)G * 4);

    hipMemsetAsync(degi, 0, (size_t)N * 4, stream);
    hipMemsetAsync(gstart, 0, (size_t)G * 4, stream);
    hipMemsetAsync(gend, 0, (size_t)G * 4, stream);

    k_deg<<<(E + 255) / 256, 256, 0, stream>>>(dst, degi, E);

    int nch = (N + 1023) / 1024;
    k_scan_a<<<nch, 256, 0, stream>>>(degi, rowptr, csums, dis, N);
    k_scan_b<<<1, 256, 0, stream>>>(csums, nch);
    k_scan_c<<<nch, 256, 0, stream>>>(rowptr, cur, csums, N, E);
    k_fill_xcd<<<2048, 256, 0, stream>>>(src, dst, cur, esrc, E, N);

    k_tabs<<<96, 256, 0, stream>>>(emb, W1, W2, T1T, W2T);

    k_fused<<<(N + 15) / 16, 256, 0, stream>>>(rowptr, esrc, nid, dis, T1T, W2T,
                                               b1, g, N);

    k_gather2<<<(N + 15) / 16, 256, 0, stream>>>(rowptr, esrc, g, dis, b2, x, N);

    k_bounds<<<(N + 255) / 256, 256, 0, stream>>>(batch, gstart, gend, N);
    k_pool2<<<G, 256, 0, stream>>>(x, gstart, gend, fcw, fcb, (float*)d_out);
}